// Round 1
// baseline (612.815 us; speedup 1.0000x reference)
//
#include <hip/hip_runtime.h>

// CausalSelfAttention: B=2, T=4096, E=768, H=12, D=64
// Pipeline: cast/transpose prep -> QKV GEMM (bf16 MFMA) -> flash attention -> proj GEMM

#define SEQT 4096
#define EMB  768
#define NHEAD 12
#define HDIM 64

typedef __attribute__((ext_vector_type(8))) short bf16x8;
typedef __attribute__((ext_vector_type(4))) float f32x4;

static __device__ __forceinline__ unsigned short f2bf(float f) {
  union { float f; unsigned u; } a; a.f = f;
  unsigned u = a.u;
  u += 0x7FFF + ((u >> 16) & 1);   // round-to-nearest-even
  return (unsigned short)(u >> 16);
}

// ---------------- prep: fp32 -> bf16 elementwise (x) ----------------
__global__ __launch_bounds__(256) void cast_bf16_kernel(
    const float* __restrict__ in, short* __restrict__ out, int n4) {
  int i = blockIdx.x * 256 + threadIdx.x;
  if (i >= n4) return;
  float4 v = ((const float4*)in)[i];
  ushort4 o;
  o.x = f2bf(v.x); o.y = f2bf(v.y); o.z = f2bf(v.z); o.w = f2bf(v.w);
  ((ushort4*)out)[i] = o;
}

// ---------------- prep: fp32 [R][C] -> bf16 [C][R] (weight transpose) ----------------
__global__ __launch_bounds__(256) void transpose_bf16_kernel(
    const float* __restrict__ in, short* __restrict__ out, int R, int C) {
  __shared__ float tile[32][33];
  int c0 = blockIdx.x * 32, r0 = blockIdx.y * 32;
  int tx = threadIdx.x, ty = threadIdx.y;   // 32 x 8
#pragma unroll
  for (int j = 0; j < 32; j += 8)
    tile[ty + j][tx] = in[(size_t)(r0 + ty + j) * C + (c0 + tx)];
  __syncthreads();
#pragma unroll
  for (int j = 0; j < 32; j += 8)
    out[(size_t)(c0 + ty + j) * R + (r0 + tx)] = (short)f2bf(tile[tx][ty + j]);
}

// ---------------- GEMM: C[M][N] = A[M][K] @ Bt[N][K]^T + bias ----------------
// 64x64 block tile, 4 waves (each: 4 m-tiles x 1 n-strip of 16), BK=32.
// MODE 0: scatter qkv into Q[b,h,t,d], K[b,h,t,d], Vt[b,h,d,t] (bf16)
// MODE 1: fp32 output [M][Ncols]
template <int MODE>
__global__ __launch_bounds__(256) void gemm_kernel(
    const short* __restrict__ A, const short* __restrict__ Bt,
    const float* __restrict__ bias, int K,
    short* __restrict__ Qg, short* __restrict__ Kg, short* __restrict__ Vtg,
    float* __restrict__ Out, int Ncols) {
  __shared__ short As[64 * 32];
  __shared__ short Bs[64 * 32];
  int tid = threadIdx.x;
  int w = tid >> 6, l = tid & 63, quad = l >> 4, lo = l & 15;
  int gm = blockIdx.x, gn = blockIdx.y;
  f32x4 acc[4] = {};
  int ra = tid >> 2, cq = tid & 3;  // staging: 64 rows x 4 sixteen-byte quarters
  const short* Aptr = A + (size_t)(gm * 64 + ra) * K + cq * 8;
  const short* Bptr = Bt + (size_t)(gn * 64 + ra) * K + cq * 8;

  for (int kk = 0; kk < K; kk += 32) {
    uint4 av = *(const uint4*)(Aptr + kk);
    uint4 bv = *(const uint4*)(Bptr + kk);
    *(uint4*)&As[ra * 32 + cq * 8] = av;
    *(uint4*)&Bs[ra * 32 + cq * 8] = bv;
    __syncthreads();
    bf16x8 bfr = *(const bf16x8*)&Bs[(w * 16 + lo) * 32 + quad * 8];
#pragma unroll
    for (int mt = 0; mt < 4; mt++) {
      bf16x8 afr = *(const bf16x8*)&As[(mt * 16 + lo) * 32 + quad * 8];
      acc[mt] = __builtin_amdgcn_mfma_f32_16x16x32_bf16(afr, bfr, acc[mt], 0, 0, 0);
    }
    __syncthreads();
  }

  int n = gn * 64 + w * 16 + lo;
  float bias_v = bias[n];
#pragma unroll
  for (int mt = 0; mt < 4; mt++) {
#pragma unroll
    for (int r = 0; r < 4; r++) {
      int m = gm * 64 + mt * 16 + quad * 4 + r;   // C/D: row=(l>>4)*4+r, col=l&15
      float v = acc[mt][r] + bias_v;
      if (MODE == 0) {
        int b = m >> 12, t = m & 4095;
        if (n < EMB) {
          int h = n >> 6, d = n & 63;
          Qg[(((size_t)b * NHEAD + h) * SEQT + t) * HDIM + d] = (short)f2bf(v);
        } else if (n < 2 * EMB) {
          int n2 = n - EMB, h = n2 >> 6, d = n2 & 63;
          Kg[(((size_t)b * NHEAD + h) * SEQT + t) * HDIM + d] = (short)f2bf(v);
        } else {
          int n2 = n - 2 * EMB, h = n2 >> 6, d = n2 & 63;
          Vtg[(((size_t)b * NHEAD + h) * HDIM + d) * SEQT + t] = (short)f2bf(v);
        }
      } else {
        Out[(size_t)m * Ncols + n] = v;
      }
    }
  }
}

// ---------------- flash attention ----------------
// grid (qtile=64, bh=24); 256 thr = 4 waves; wave owns 16 q rows; kv step 32.
__global__ __launch_bounds__(256) void attn_kernel(
    const short* __restrict__ Qg, const short* __restrict__ Kg,
    const short* __restrict__ Vtg, short* __restrict__ Y) {
  __shared__ short Ks[32 * 64];      // [kv][d]
  __shared__ short Vs[64 * 32];      // [d][kv]  (transposed V)
  __shared__ short Ps[4][16 * 32];   // per-wave P round-trip [q][kv]
  int tid = threadIdx.x;
  int w = tid >> 6, l = tid & 63, quad = l >> 4, lo = l & 15;
  int q0 = blockIdx.x * 64;
  int bh = blockIdx.y;
  int b = bh / NHEAD, h = bh % NHEAD;
  const short* Qbase = Qg + (size_t)bh * SEQT * HDIM;
  const short* Kbase = Kg + (size_t)bh * SEQT * HDIM;
  const short* Vbase = Vtg + (size_t)bh * HDIM * SEQT;

  int qrow = q0 + w * 16 + lo;       // A-operand: m = lane&15
  bf16x8 qf0 = *(const bf16x8*)&Qbase[(size_t)qrow * 64 + quad * 8];
  bf16x8 qf1 = *(const bf16x8*)&Qbase[(size_t)qrow * 64 + 32 + quad * 8];

  f32x4 O[4] = {};
  float m_r[4] = {-1e30f, -1e30f, -1e30f, -1e30f};
  float l_r[4] = {0.f, 0.f, 0.f, 0.f};

  int krow = tid >> 3, kcq = tid & 7;  // K staging: 32 rows x 8 quarters
  int vrow = tid >> 2, vcq = tid & 3;  // Vt staging: 64 rows x 4 quarters

  int nkv = q0 + 64;
  for (int kv0 = 0; kv0 < nkv; kv0 += 32) {
    uint4 kv_ = *(const uint4*)&Kbase[(size_t)(kv0 + krow) * 64 + kcq * 8];
    uint4 vv_ = *(const uint4*)&Vbase[(size_t)vrow * SEQT + kv0 + vcq * 8];
    *(uint4*)&Ks[krow * 64 + kcq * 8] = kv_;
    *(uint4*)&Vs[vrow * 32 + vcq * 8] = vv_;
    __syncthreads();

    // S = Q @ K^T  (two 16x16 kv tiles, contraction D=64 in two k-steps)
    f32x4 s0 = {}, s1 = {};
    {
      bf16x8 k0a = *(const bf16x8*)&Ks[lo * 64 + quad * 8];
      bf16x8 k0b = *(const bf16x8*)&Ks[lo * 64 + 32 + quad * 8];
      s0 = __builtin_amdgcn_mfma_f32_16x16x32_bf16(qf0, k0a, s0, 0, 0, 0);
      s0 = __builtin_amdgcn_mfma_f32_16x16x32_bf16(qf1, k0b, s0, 0, 0, 0);
      bf16x8 k1a = *(const bf16x8*)&Ks[(16 + lo) * 64 + quad * 8];
      bf16x8 k1b = *(const bf16x8*)&Ks[(16 + lo) * 64 + 32 + quad * 8];
      s1 = __builtin_amdgcn_mfma_f32_16x16x32_bf16(qf0, k1a, s1, 0, 0, 0);
      s1 = __builtin_amdgcn_mfma_f32_16x16x32_bf16(qf1, k1b, s1, 0, 0, 0);
    }

    int qp = q0 + w * 16 + quad * 4;   // C/D: row = quad*4 + r, col = lo
    float al[4];
#pragma unroll
    for (int r = 0; r < 4; r++) {
      int qpr = qp + r;
      float a = (kv0 + lo <= qpr) ? s0[r] * 0.125f : -1e30f;
      float c = (kv0 + 16 + lo <= qpr) ? s1[r] * 0.125f : -1e30f;
      float mxr = fmaxf(a, c);
      mxr = fmaxf(mxr, __shfl_xor(mxr, 1));
      mxr = fmaxf(mxr, __shfl_xor(mxr, 2));
      mxr = fmaxf(mxr, __shfl_xor(mxr, 4));
      mxr = fmaxf(mxr, __shfl_xor(mxr, 8));
      float mn = fmaxf(m_r[r], mxr);
      al[r] = __expf(m_r[r] - mn);
      m_r[r] = mn;
      float p0 = __expf(a - mn), p1 = __expf(c - mn);
      float sm = p0 + p1;
      sm += __shfl_xor(sm, 1);
      sm += __shfl_xor(sm, 2);
      sm += __shfl_xor(sm, 4);
      sm += __shfl_xor(sm, 8);
      l_r[r] = l_r[r] * al[r] + sm;
      Ps[w][(quad * 4 + r) * 32 + lo] = (short)f2bf(p0);
      Ps[w][(quad * 4 + r) * 32 + 16 + lo] = (short)f2bf(p1);
    }
#pragma unroll
    for (int dt = 0; dt < 4; dt++) {
#pragma unroll
      for (int r = 0; r < 4; r++) O[dt][r] *= al[r];
    }
    __syncthreads();   // P LDS write -> A-layout read

    // O += P @ V   (P: [16 q][32 kv] A-layout; V via transposed LDS tile)
    bf16x8 pf = *(const bf16x8*)&Ps[w][lo * 32 + quad * 8];
#pragma unroll
    for (int dt = 0; dt < 4; dt++) {
      bf16x8 vf = *(const bf16x8*)&Vs[(dt * 16 + lo) * 32 + quad * 8];
      O[dt] = __builtin_amdgcn_mfma_f32_16x16x32_bf16(pf, vf, O[dt], 0, 0, 0);
    }
    __syncthreads();   // protect Ks/Vs before next staging
  }

#pragma unroll
  for (int dt = 0; dt < 4; dt++) {
#pragma unroll
    for (int r = 0; r < 4; r++) {
      int q = q0 + w * 16 + quad * 4 + r;
      int e = h * 64 + dt * 16 + lo;
      Y[((size_t)b * SEQT + q) * EMB + e] = (short)f2bf(O[dt][r] / l_r[r]);
    }
  }
}

extern "C" void kernel_launch(void* const* d_in, const int* in_sizes, int n_in,
                              void* d_out, int out_size, void* d_ws, size_t ws_size,
                              hipStream_t stream) {
  const float* x      = (const float*)d_in[0];   // [2,4096,768]
  const float* W_attn = (const float*)d_in[1];   // [768,2304]
  const float* b_attn = (const float*)d_in[2];   // [2304]
  const float* W_proj = (const float*)d_in[3];   // [768,768]
  const float* b_proj = (const float*)d_in[4];   // [768]
  float* out = (float*)d_out;                    // [2,4096,768] fp32

  char* ws = (char*)d_ws;
  // byte offsets (all 16B aligned)
  short* x_bf = (short*)(ws + 0);           // 8192x768 bf16   = 12,582,912 B
  short* Wt_a = (short*)(ws + 12582912);    // 2304x768 bf16   =  3,538,944 B
  short* Wt_p = (short*)(ws + 16121856);    // 768x768  bf16   =  1,179,648 B
  short* Qg   = (short*)(ws + 17301504);    // [2,12,4096,64]  = 12,582,912 B
  short* Kg   = (short*)(ws + 29884416);    // [2,12,4096,64]
  short* Vtg  = (short*)(ws + 42467328);    // [2,12,64,4096]
  short* Ybf  = (short*)(ws + 55050240);    // 8192x768 bf16
  // total 67,633,152 B

  cast_bf16_kernel<<<6144, 256, 0, stream>>>(x, x_bf, 1572864);
  transpose_bf16_kernel<<<dim3(72, 24), dim3(32, 8), 0, stream>>>(W_attn, Wt_a, 768, 2304);
  transpose_bf16_kernel<<<dim3(24, 24), dim3(32, 8), 0, stream>>>(W_proj, Wt_p, 768, 768);

  gemm_kernel<0><<<dim3(128, 36), 256, 0, stream>>>(x_bf, Wt_a, b_attn, 768,
                                                    Qg, Kg, Vtg, nullptr, 0);
  attn_kernel<<<dim3(64, 24), 256, 0, stream>>>(Qg, Kg, Vtg, Ybf);
  gemm_kernel<1><<<dim3(128, 12), 256, 0, stream>>>(Ybf, Wt_p, b_proj, 768,
                                                    nullptr, nullptr, nullptr, out, 768);
}

// Round 2
// 321.973 us; speedup vs baseline: 1.9033x; 1.9033x over previous
//
#include <hip/hip_runtime.h>

// CausalSelfAttention: B=2, T=4096, E=768, H=12, D=64
// Pipeline: cast/transpose prep -> QKV GEMM (bf16 MFMA) -> flash attention (S^T form) -> proj GEMM

#define SEQT 4096
#define EMB  768
#define NHEAD 12
#define HDIM 64

typedef __attribute__((ext_vector_type(8))) short bf16x8;
typedef __attribute__((ext_vector_type(4))) float f32x4;

static __device__ __forceinline__ unsigned short f2bf(float f) {
  union { float f; unsigned u; } a; a.f = f;
  unsigned u = a.u;
  u += 0x7FFF + ((u >> 16) & 1);   // round-to-nearest-even
  return (unsigned short)(u >> 16);
}

// ---------------- prep: fp32 -> bf16 elementwise (x) ----------------
__global__ __launch_bounds__(256) void cast_bf16_kernel(
    const float* __restrict__ in, short* __restrict__ out, int n4) {
  int i = blockIdx.x * 256 + threadIdx.x;
  if (i >= n4) return;
  float4 v = ((const float4*)in)[i];
  ushort4 o;
  o.x = f2bf(v.x); o.y = f2bf(v.y); o.z = f2bf(v.z); o.w = f2bf(v.w);
  ((ushort4*)out)[i] = o;
}

// ---------------- prep: fp32 [R][C] -> bf16 [C][R] (weight transpose) ----------------
__global__ __launch_bounds__(256) void transpose_bf16_kernel(
    const float* __restrict__ in, short* __restrict__ out, int R, int C) {
  __shared__ float tile[32][33];
  int c0 = blockIdx.x * 32, r0 = blockIdx.y * 32;
  int tx = threadIdx.x, ty = threadIdx.y;   // 32 x 8
#pragma unroll
  for (int j = 0; j < 32; j += 8)
    tile[ty + j][tx] = in[(size_t)(r0 + ty + j) * C + (c0 + tx)];
  __syncthreads();
#pragma unroll
  for (int j = 0; j < 32; j += 8)
    out[(size_t)(c0 + ty + j) * R + (r0 + tx)] = (short)f2bf(tile[tx][ty + j]);
}

// ---------------- GEMM: C[M][N] = A[M][K] @ Bt[N][K]^T + bias ----------------
// 64x64 block tile, 4 waves, BK=32. LDS rows padded 32->40 shorts (2-way banks).
// MODE 0: scatter qkv into Q[b,h,t,d], K[b,h,t,d], Vt[b,h,d,t] (bf16)
// MODE 1: fp32 output [M][Ncols]
#define GP 40
template <int MODE>
__global__ __launch_bounds__(256) void gemm_kernel(
    const short* __restrict__ A, const short* __restrict__ Bt,
    const float* __restrict__ bias, int K,
    short* __restrict__ Qg, short* __restrict__ Kg, short* __restrict__ Vtg,
    float* __restrict__ Out, int Ncols) {
  __shared__ short As[64 * GP];
  __shared__ short Bs[64 * GP];
  int tid = threadIdx.x;
  int w = tid >> 6, l = tid & 63, quad = l >> 4, lo = l & 15;
  int gm = blockIdx.x, gn = blockIdx.y;
  f32x4 acc[4] = {};
  int ra = tid >> 2, cq = tid & 3;
  const short* Aptr = A + (size_t)(gm * 64 + ra) * K + cq * 8;
  const short* Bptr = Bt + (size_t)(gn * 64 + ra) * K + cq * 8;

  for (int kk = 0; kk < K; kk += 32) {
    uint4 av = *(const uint4*)(Aptr + kk);
    uint4 bv = *(const uint4*)(Bptr + kk);
    *(uint4*)&As[ra * GP + cq * 8] = av;
    *(uint4*)&Bs[ra * GP + cq * 8] = bv;
    __syncthreads();
    bf16x8 bfr = *(const bf16x8*)&Bs[(w * 16 + lo) * GP + quad * 8];
#pragma unroll
    for (int mt = 0; mt < 4; mt++) {
      bf16x8 afr = *(const bf16x8*)&As[(mt * 16 + lo) * GP + quad * 8];
      acc[mt] = __builtin_amdgcn_mfma_f32_16x16x32_bf16(afr, bfr, acc[mt], 0, 0, 0);
    }
    __syncthreads();
  }

  int n = gn * 64 + w * 16 + lo;
  float bias_v = bias[n];
#pragma unroll
  for (int mt = 0; mt < 4; mt++) {
#pragma unroll
    for (int r = 0; r < 4; r++) {
      int m = gm * 64 + mt * 16 + quad * 4 + r;   // C/D: row=(l>>4)*4+r, col=l&15
      float v = acc[mt][r] + bias_v;
      if (MODE == 0) {
        int b = m >> 12, t = m & 4095;
        if (n < EMB) {
          int h = n >> 6, d = n & 63;
          Qg[(((size_t)b * NHEAD + h) * SEQT + t) * HDIM + d] = (short)f2bf(v);
        } else if (n < 2 * EMB) {
          int n2 = n - EMB, h = n2 >> 6, d = n2 & 63;
          Kg[(((size_t)b * NHEAD + h) * SEQT + t) * HDIM + d] = (short)f2bf(v);
        } else {
          int n2 = n - 2 * EMB, h = n2 >> 6, d = n2 & 63;
          Vtg[(((size_t)b * NHEAD + h) * HDIM + d) * SEQT + t] = (short)f2bf(v);
        }
      } else {
        Out[(size_t)m * Ncols + n] = v;
      }
    }
  }
}

// ---------------- flash attention, S^T formulation ----------------
// Block: 128 q rows, 4 waves (32 q each, 2 subtiles of 16). kv-step 64.
// S^T = mfma(K_frag, Q_frag): C/D col=q (lane&15), row=kv (quad*4+r).
// Softmax row = kv spans regs+quads: fold 16 in-reg, 2 shuffles. m/l scalar per lane.
// O^T = mfma(Vt_frag, P_frag) accumulated in C/D layout (row=d, col=q).
#define AP 72   // padded LDS row length (shorts) for 64-wide tiles
__global__ __launch_bounds__(256, 3) void attn_kernel(
    const short* __restrict__ Qg, const short* __restrict__ Kg,
    const short* __restrict__ Vtg, short* __restrict__ Y) {
  __shared__ short Ks[64 * AP];
  __shared__ short Vs[64 * AP];
  __shared__ short Ps[4][32 * AP];
  int tid = threadIdx.x;
  int w = tid >> 6, l = tid & 63, quad = l >> 4, lo = l & 15;
  int bh = blockIdx.x;
  int y = blockIdx.y;
  int qt = (y & 1) ? (31 - (y >> 1)) : (y >> 1);   // interleave big/small for balance
  int q0 = qt * 128;
  int b = bh / NHEAD, h = bh % NHEAD;
  const short* Qbase = Qg + (size_t)bh * SEQT * HDIM;
  const short* Kbase = Kg + (size_t)bh * SEQT * HDIM;
  const short* Vbase = Vtg + (size_t)bh * HDIM * SEQT;
  short* Pw = &Ps[w][0];

  int qw = q0 + w * 32;
  bf16x8 qf[2][2];
#pragma unroll
  for (int s = 0; s < 2; s++) {
    const short* qp = &Qbase[(size_t)(qw + s * 16 + lo) * HDIM + quad * 8];
    qf[s][0] = *(const bf16x8*)qp;
    qf[s][1] = *(const bf16x8*)(qp + 32);
  }

  f32x4 O[2][4] = {};                       // [qsub][dtile], O^T: row=d, col=q
  float m_s[2] = {-1e30f, -1e30f};
  float l_s[2] = {0.f, 0.f};

  int sr = tid >> 2, sc = tid & 3;          // staging: 64 rows x (2 chunks of 16B)
  const float SC = 0.18033688011112042f;    // (1/sqrt(64)) * log2(e)

  int nkv = q0 + 128;
  for (int kv0 = 0; kv0 < nkv; kv0 += 64) {
    const short* kg = &Kbase[(size_t)(kv0 + sr) * HDIM];
    const short* vg = &Vbase[(size_t)sr * SEQT + kv0];
    uint4 k0 = *(const uint4*)(kg + sc * 8);
    uint4 k1 = *(const uint4*)(kg + sc * 8 + 32);
    uint4 v0 = *(const uint4*)(vg + sc * 8);
    uint4 v1 = *(const uint4*)(vg + sc * 8 + 32);
    *(uint4*)&Ks[sr * AP + sc * 8] = k0;
    *(uint4*)&Ks[sr * AP + sc * 8 + 32] = k1;
    *(uint4*)&Vs[sr * AP + sc * 8] = v0;
    *(uint4*)&Vs[sr * AP + sc * 8 + 32] = v1;
    __syncthreads();

    // S^T = K @ Q^T over 4 kv-tiles x 2 k-halves
    f32x4 st[2][4] = {};
#pragma unroll
    for (int t = 0; t < 4; t++) {
      const short* kp = &Ks[(t * 16 + lo) * AP + quad * 8];
      bf16x8 ka = *(const bf16x8*)kp;
      bf16x8 kb2 = *(const bf16x8*)(kp + 32);
      st[0][t] = __builtin_amdgcn_mfma_f32_16x16x32_bf16(ka,  qf[0][0], st[0][t], 0, 0, 0);
      st[0][t] = __builtin_amdgcn_mfma_f32_16x16x32_bf16(kb2, qf[0][1], st[0][t], 0, 0, 0);
      st[1][t] = __builtin_amdgcn_mfma_f32_16x16x32_bf16(ka,  qf[1][0], st[1][t], 0, 0, 0);
      st[1][t] = __builtin_amdgcn_mfma_f32_16x16x32_bf16(kb2, qf[1][1], st[1][t], 0, 0, 0);
    }

    // online softmax per q-subtile (lane q = qs+lo; kv in regs+quads)
#pragma unroll
    for (int s = 0; s < 2; s++) {
      int qs = qw + s * 16;
      float mx = -1e30f;
#pragma unroll
      for (int t = 0; t < 4; t++) {
        int kb = kv0 + t * 16;
        if (kb < qs) {                       // fully valid tile
#pragma unroll
          for (int r = 0; r < 4; r++) {
            st[s][t][r] *= SC;
            mx = fmaxf(mx, st[s][t][r]);
          }
        } else if (kb == qs) {               // diagonal tile: kv<=q  <=>  quad*4+r <= lo
#pragma unroll
          for (int r = 0; r < 4; r++) {
            st[s][t][r] = (quad * 4 + r <= lo) ? st[s][t][r] * SC : -1e30f;
            mx = fmaxf(mx, st[s][t][r]);
          }
        } else {                             // fully masked
#pragma unroll
          for (int r = 0; r < 4; r++) st[s][t][r] = -1e30f;
        }
      }
      mx = fmaxf(mx, __shfl_xor(mx, 16));
      mx = fmaxf(mx, __shfl_xor(mx, 32));
      float mn = fmaxf(m_s[s], mx);
      float al = __builtin_amdgcn_exp2f(m_s[s] - mn);
      m_s[s] = mn;
      float sm = 0.f;
#pragma unroll
      for (int t = 0; t < 4; t++) {
        int kb = kv0 + t * 16;
        ushort4 pk;
        if (kb <= qs) {
          float p0 = __builtin_amdgcn_exp2f(st[s][t][0] - mn);
          float p1 = __builtin_amdgcn_exp2f(st[s][t][1] - mn);
          float p2 = __builtin_amdgcn_exp2f(st[s][t][2] - mn);
          float p3 = __builtin_amdgcn_exp2f(st[s][t][3] - mn);
          sm += (p0 + p1) + (p2 + p3);
          pk.x = f2bf(p0); pk.y = f2bf(p1); pk.z = f2bf(p2); pk.w = f2bf(p3);
        } else {
          pk.x = 0; pk.y = 0; pk.z = 0; pk.w = 0;
        }
        // P^T pack: 4 consecutive kv for q=lo -> one b64 write
        *(ushort4*)&Pw[(s * 16 + lo) * AP + t * 16 + quad * 4] = pk;
      }
      sm += __shfl_xor(sm, 16);
      sm += __shfl_xor(sm, 32);
      l_s[s] = l_s[s] * al + sm;
#pragma unroll
      for (int dt = 0; dt < 4; dt++)
#pragma unroll
        for (int r = 0; r < 4; r++) O[s][dt][r] *= al;
    }

    // Pw is wave-private: in-wave lgkmcnt orders write->read, no barrier.
    bf16x8 pfr[2][2];
#pragma unroll
    for (int s = 0; s < 2; s++) {
      const short* pp = &Pw[(s * 16 + lo) * AP + quad * 8];
      pfr[s][0] = *(const bf16x8*)pp;
      pfr[s][1] = *(const bf16x8*)(pp + 32);
    }
#pragma unroll
    for (int dt = 0; dt < 4; dt++) {
      const short* vp = &Vs[(dt * 16 + lo) * AP + quad * 8];
      bf16x8 va = *(const bf16x8*)vp;
      bf16x8 vb = *(const bf16x8*)(vp + 32);
#pragma unroll
      for (int s = 0; s < 2; s++) {
        O[s][dt] = __builtin_amdgcn_mfma_f32_16x16x32_bf16(va, pfr[s][0], O[s][dt], 0, 0, 0);
        O[s][dt] = __builtin_amdgcn_mfma_f32_16x16x32_bf16(vb, pfr[s][1], O[s][dt], 0, 0, 0);
      }
    }
    __syncthreads();   // Ks/Vs reads done before next staging
  }

  // epilogue: O^T[d][q] -> Y[b][q][h*64+d], 4 consecutive d packed per store
#pragma unroll
  for (int s = 0; s < 2; s++) {
    float rl = 1.f / l_s[s];
    int q = qw + s * 16 + lo;
    short* yp = &Y[((size_t)b * SEQT + q) * EMB + h * 64 + quad * 4];
#pragma unroll
    for (int dt = 0; dt < 4; dt++) {
      ushort4 o;
      o.x = f2bf(O[s][dt][0] * rl);
      o.y = f2bf(O[s][dt][1] * rl);
      o.z = f2bf(O[s][dt][2] * rl);
      o.w = f2bf(O[s][dt][3] * rl);
      *(ushort4*)(yp + dt * 16) = o;
    }
  }
}

extern "C" void kernel_launch(void* const* d_in, const int* in_sizes, int n_in,
                              void* d_out, int out_size, void* d_ws, size_t ws_size,
                              hipStream_t stream) {
  const float* x      = (const float*)d_in[0];   // [2,4096,768]
  const float* W_attn = (const float*)d_in[1];   // [768,2304]
  const float* b_attn = (const float*)d_in[2];   // [2304]
  const float* W_proj = (const float*)d_in[3];   // [768,768]
  const float* b_proj = (const float*)d_in[4];   // [768]
  float* out = (float*)d_out;                    // [2,4096,768] fp32

  char* ws = (char*)d_ws;
  short* x_bf = (short*)(ws + 0);           // 8192x768 bf16
  short* Wt_a = (short*)(ws + 12582912);    // 2304x768 bf16
  short* Wt_p = (short*)(ws + 16121856);    // 768x768  bf16
  short* Qg   = (short*)(ws + 17301504);    // [2,12,4096,64]
  short* Kg   = (short*)(ws + 29884416);    // [2,12,4096,64]
  short* Vtg  = (short*)(ws + 42467328);    // [2,12,64,4096]
  short* Ybf  = (short*)(ws + 55050240);    // 8192x768 bf16

  cast_bf16_kernel<<<6144, 256, 0, stream>>>(x, x_bf, 1572864);
  transpose_bf16_kernel<<<dim3(72, 24), dim3(32, 8), 0, stream>>>(W_attn, Wt_a, 768, 2304);
  transpose_bf16_kernel<<<dim3(24, 24), dim3(32, 8), 0, stream>>>(W_proj, Wt_p, 768, 768);

  gemm_kernel<0><<<dim3(128, 36), 256, 0, stream>>>(x_bf, Wt_a, b_attn, 768,
                                                    Qg, Kg, Vtg, nullptr, 0);
  attn_kernel<<<dim3(24, 32), 256, 0, stream>>>(Qg, Kg, Vtg, Ybf);
  gemm_kernel<1><<<dim3(128, 12), 256, 0, stream>>>(Ybf, Wt_p, b_proj, 768,
                                                    nullptr, nullptr, nullptr, out, 768);
}